// Round 5
// baseline (24.856 us; speedup 1.0000x reference)
//
#include <hip/hip_runtime.h>

#define NQ 4
#define DIM 16
#define TPB 256

// ---------------------------------------------------------------------------
// Fully fused, LDS-free kernel: one batch row per thread, full 16-dim complex
// statevector simulation in registers. Constant gate angles come in via
// s_load (uniform) + __sincosf; CNOTs are compile-time register permutations.
// ---------------------------------------------------------------------------

template <int BIT>
__device__ __forceinline__ void rz_gate(float* re, float* im, float cz, float sz) {
    // amp *= e^{-i t/2} on BIT==0, e^{+i t/2} on BIT==1
#pragma unroll
    for (int k = 0; k < DIM; ++k) {
        const float ss = (k & BIT) ? -sz : sz;
        const float nr = re[k] * cz + im[k] * ss;
        const float ni = im[k] * cz - re[k] * ss;
        re[k] = nr; im[k] = ni;
    }
}

template <int BIT>
__device__ __forceinline__ void ry_gate(float* re, float* im, float cy, float sy) {
#pragma unroll
    for (int k = 0; k < DIM; ++k) {
        if (!(k & BIT)) {
            const int k1 = k | BIT;
            const float r0 = re[k], i0 = im[k], r1 = re[k1], i1 = im[k1];
            re[k]  = cy * r0 - sy * r1;  im[k]  = cy * i0 - sy * i1;
            re[k1] = sy * r0 + cy * r1;  im[k1] = sy * i0 + cy * i1;
        }
    }
}

template <int CB, int TB>
__device__ __forceinline__ void cnot(float* re, float* im) {
    float tr[DIM], ti[DIM];
#pragma unroll
    for (int k = 0; k < DIM; ++k) {
        const int ks = (k & CB) ? (k ^ TB) : k;   // compile-time after unroll
        tr[k] = re[ks]; ti[k] = im[ks];
    }
#pragma unroll
    for (int k = 0; k < DIM; ++k) { re[k] = tr[k]; im[k] = ti[k]; }
}

__global__ __launch_bounds__(TPB, 4) void qnn_fused(
    const float* __restrict__ x, const float* __restrict__ fm_w,
    const float* __restrict__ fm_b, const float* __restrict__ w,
    float* __restrict__ out, int B) {
    const long long b = (long long)blockIdx.x * TPB + threadIdx.x;
    if (b >= B) return;

    // --- angles GEMV: 4 dots of length 64; fm_w uniform -> s_load ---
    float acc[NQ];
#pragma unroll
    for (int q = 0; q < NQ; ++q) acc[q] = fm_b[q];

    const float4* __restrict__ x4 = (const float4*)(x + b * 64);
    const float4* __restrict__ w4 = (const float4*)fm_w;
#pragma unroll
    for (int t = 0; t < 16; ++t) {
        const float4 xv = x4[t];
#pragma unroll
        for (int q = 0; q < NQ; ++q) {
            const float4 wv = w4[q * 16 + t];
            acc[q] += xv.x * wv.x + xv.y * wv.y + xv.z * wv.z + xv.w * wv.w;
        }
    }

    // --- data-dependent RY layer == real product state (qubit 0 = MSB) ---
    float c[NQ], s[NQ];
#pragma unroll
    for (int q = 0; q < NQ; ++q) __sincosf(0.5f * acc[q], &s[q], &c[q]);

    float p01[4], p23[4];
#pragma unroll
    for (int u = 0; u < 4; ++u) {
        p01[u] = ((u & 2) ? s[0] : c[0]) * ((u & 1) ? s[1] : c[1]);
        p23[u] = ((u & 2) ? s[2] : c[2]) * ((u & 1) ? s[3] : c[3]);
    }
    float st[DIM];
#pragma unroll
    for (int i = 0; i < DIM; ++i) st[i] = p01[i >> 2] * p23[i & 3];

    // --- constant circuit, angles uniform (s_load + __sincosf) ---
    // gate angle flat index: (layer*4 + q)*2 + rot
    float re[DIM], im[DIM];

    // layer 1, q0 RZ applied to the real state directly
    {
        float sz, cz; __sincosf(0.5f * w[0], &sz, &cz);
#pragma unroll
        for (int k = 0; k < DIM; ++k) {
            re[k] = st[k] * cz;
            im[k] = (k & 8) ? st[k] * sz : -(st[k] * sz);
        }
    }
    {
        float sy, cy; __sincosf(0.5f * w[1], &sy, &cy);
        ry_gate<8>(re, im, cy, sy);
    }
    {
        float sz, cz; __sincosf(0.5f * w[2], &sz, &cz);
        rz_gate<4>(re, im, cz, sz);
        float sy, cy; __sincosf(0.5f * w[3], &sy, &cy);
        ry_gate<4>(re, im, cy, sy);
    }
    {
        float sz, cz; __sincosf(0.5f * w[4], &sz, &cz);
        rz_gate<2>(re, im, cz, sz);
        float sy, cy; __sincosf(0.5f * w[5], &sy, &cy);
        ry_gate<2>(re, im, cy, sy);
    }
    {
        float sz, cz; __sincosf(0.5f * w[6], &sz, &cz);
        rz_gate<1>(re, im, cz, sz);
        float sy, cy; __sincosf(0.5f * w[7], &sy, &cy);
        ry_gate<1>(re, im, cy, sy);
    }

    // CNOT chain (free register permutations)
    cnot<8, 4>(re, im);
    cnot<4, 2>(re, im);
    cnot<2, 1>(re, im);

    // layer 2
    {
        float sz, cz; __sincosf(0.5f * w[8], &sz, &cz);
        rz_gate<8>(re, im, cz, sz);
        float sy, cy; __sincosf(0.5f * w[9], &sy, &cy);
        ry_gate<8>(re, im, cy, sy);
    }
    {
        float sz, cz; __sincosf(0.5f * w[10], &sz, &cz);
        rz_gate<4>(re, im, cz, sz);
        float sy, cy; __sincosf(0.5f * w[11], &sy, &cy);
        ry_gate<4>(re, im, cy, sy);
    }
    {
        float sz, cz; __sincosf(0.5f * w[12], &sz, &cz);
        rz_gate<2>(re, im, cz, sz);
        float sy, cy; __sincosf(0.5f * w[13], &sy, &cy);
        ry_gate<2>(re, im, cy, sy);
    }
    {
        float sz, cz; __sincosf(0.5f * w[14], &sz, &cz);
        rz_gate<1>(re, im, cz, sz);
        float sy, cy; __sincosf(0.5f * w[15], &sy, &cy);
        ry_gate<1>(re, im, cy, sy);
    }

    // --- probabilities and the 4 Z-expectations ---
    float o0 = 0.f, o1 = 0.f, o2 = 0.f, o3 = 0.f;
#pragma unroll
    for (int k = 0; k < DIM; ++k) {
        const float pk = re[k] * re[k] + im[k] * im[k];
        o0 += (k & 8) ? -pk : pk;
        o1 += (k & 4) ? -pk : pk;
        o2 += (k & 2) ? -pk : pk;
        o3 += (k & 1) ? -pk : pk;
    }

    *(float4*)(out + b * 4) = make_float4(o0, o1, o2, o3);
}

extern "C" void kernel_launch(void* const* d_in, const int* in_sizes, int n_in,
                              void* d_out, int out_size, void* d_ws, size_t ws_size,
                              hipStream_t stream) {
    const float* x    = (const float*)d_in[0];
    const float* fm_w = (const float*)d_in[1];
    const float* fm_b = (const float*)d_in[2];
    const float* qw   = (const float*)d_in[3];
    float* out = (float*)d_out;

    const int B = in_sizes[0] / 64;

    qnn_fused<<<(B + TPB - 1) / TPB, TPB, 0, stream>>>(x, fm_w, fm_b, qw, out, B);
}

// Round 6
// 24.780 us; speedup vs baseline: 1.0031x; 1.0031x over previous
//
#include <hip/hip_runtime.h>

#define NQ 4
#define DIM 16
#define TPB 256

// ---------------------------------------------------------------------------
// Fully fused, LDS-free, barrier-free kernel.
// Load phase: 8 lanes cooperate per row (each lane 8 consecutive floats =
// 32-B stride -> 16 cache lines per load instr instead of 64). Partial dots
// are reduced across the 8-lane group with shfl_xor (DPP). After 8 iters,
// lane l owns row wbase + (l>>3)*8 + (l&7); stores are lane-contiguous.
// Sim phase: full 16-dim complex statevector in registers (R5, verified).
// ---------------------------------------------------------------------------

template <int BIT>
__device__ __forceinline__ void rz_gate(float* re, float* im, float cz, float sz) {
#pragma unroll
    for (int k = 0; k < DIM; ++k) {
        const float ss = (k & BIT) ? -sz : sz;
        const float nr = re[k] * cz + im[k] * ss;
        const float ni = im[k] * cz - re[k] * ss;
        re[k] = nr; im[k] = ni;
    }
}

template <int BIT>
__device__ __forceinline__ void ry_gate(float* re, float* im, float cy, float sy) {
#pragma unroll
    for (int k = 0; k < DIM; ++k) {
        if (!(k & BIT)) {
            const int k1 = k | BIT;
            const float r0 = re[k], i0 = im[k], r1 = re[k1], i1 = im[k1];
            re[k]  = cy * r0 - sy * r1;  im[k]  = cy * i0 - sy * i1;
            re[k1] = sy * r0 + cy * r1;  im[k1] = sy * i0 + cy * i1;
        }
    }
}

template <int CB, int TB>
__device__ __forceinline__ void cnot(float* re, float* im) {
    float tr[DIM], ti[DIM];
#pragma unroll
    for (int k = 0; k < DIM; ++k) {
        const int ks = (k & CB) ? (k ^ TB) : k;
        tr[k] = re[ks]; ti[k] = im[ks];
    }
#pragma unroll
    for (int k = 0; k < DIM; ++k) { re[k] = tr[k]; im[k] = ti[k]; }
}

__device__ __forceinline__ float dot44(const float4 a, const float4 w) {
    return a.x * w.x + a.y * w.y + a.z * w.z + a.w * w.w;
}

__global__ __launch_bounds__(TPB, 4) void qnn_fused(
    const float* __restrict__ x, const float* __restrict__ fm_w,
    const float* __restrict__ fm_b, const float* __restrict__ w,
    float* __restrict__ out, int B) {
    const int tid = threadIdx.x;
    const int lane = tid & 63;
    const int g = lane >> 3;   // 8-lane group id (0..7)
    const int o = lane & 7;    // slot within group
    const long long wbase = (long long)blockIdx.x * TPB + (tid & ~63);

    // --- hoisted fm_w fragment: w[q][o*8 .. o*8+7], lane-dependent, 1 KB in L1
    const float4* __restrict__ w4 = (const float4*)fm_w;
    float4 wf[8];
#pragma unroll
    for (int q = 0; q < NQ; ++q) {
        wf[q * 2 + 0] = w4[q * 16 + o * 2 + 0];
        wf[q * 2 + 1] = w4[q * 16 + o * 2 + 1];
    }

    // --- cooperative GEMV: iter i processes rows {wbase + g*8 + i} ---
    float ang[NQ] = {0.f, 0.f, 0.f, 0.f};
#pragma unroll
    for (int i = 0; i < 8; ++i) {
        const long long r = wbase + g * 8 + i;
        float4 xa = make_float4(0.f, 0.f, 0.f, 0.f), xb = xa;
        if (r < B) {
            const float4* __restrict__ xp = (const float4*)(x + r * 64) + o * 2;
            xa = xp[0]; xb = xp[1];
        }
        float d[NQ];
#pragma unroll
        for (int q = 0; q < NQ; ++q)
            d[q] = dot44(xa, wf[q * 2]) + dot44(xb, wf[q * 2 + 1]);
        // reduce over the 8-lane group (masks 1,2,4 -> DPP)
#pragma unroll
        for (int m = 1; m <= 4; m <<= 1) {
#pragma unroll
            for (int q = 0; q < NQ; ++q) d[q] += __shfl_xor(d[q], m);
        }
        if (o == i) {
#pragma unroll
            for (int q = 0; q < NQ; ++q) ang[q] = d[q] + fm_b[q];
        }
    }

    const long long b = wbase + g * 8 + o;   // row this lane owns
    if (b >= B) return;

    // --- data-dependent RY layer == real product state (qubit 0 = MSB) ---
    float c[NQ], s[NQ];
#pragma unroll
    for (int q = 0; q < NQ; ++q) __sincosf(0.5f * ang[q], &s[q], &c[q]);

    float p01[4], p23[4];
#pragma unroll
    for (int u = 0; u < 4; ++u) {
        p01[u] = ((u & 2) ? s[0] : c[0]) * ((u & 1) ? s[1] : c[1]);
        p23[u] = ((u & 2) ? s[2] : c[2]) * ((u & 1) ? s[3] : c[3]);
    }
    float st[DIM];
#pragma unroll
    for (int i = 0; i < DIM; ++i) st[i] = p01[i >> 2] * p23[i & 3];

    // --- constant circuit in registers; angles uniform (s_load + sincos) ---
    float re[DIM], im[DIM];
    {
        float sz, cz; __sincosf(0.5f * w[0], &sz, &cz);
#pragma unroll
        for (int k = 0; k < DIM; ++k) {
            re[k] = st[k] * cz;
            im[k] = (k & 8) ? st[k] * sz : -(st[k] * sz);
        }
    }
    {
        float sy, cy; __sincosf(0.5f * w[1], &sy, &cy);
        ry_gate<8>(re, im, cy, sy);
    }
    {
        float sz, cz; __sincosf(0.5f * w[2], &sz, &cz);
        rz_gate<4>(re, im, cz, sz);
        float sy, cy; __sincosf(0.5f * w[3], &sy, &cy);
        ry_gate<4>(re, im, cy, sy);
    }
    {
        float sz, cz; __sincosf(0.5f * w[4], &sz, &cz);
        rz_gate<2>(re, im, cz, sz);
        float sy, cy; __sincosf(0.5f * w[5], &sy, &cy);
        ry_gate<2>(re, im, cy, sy);
    }
    {
        float sz, cz; __sincosf(0.5f * w[6], &sz, &cz);
        rz_gate<1>(re, im, cz, sz);
        float sy, cy; __sincosf(0.5f * w[7], &sy, &cy);
        ry_gate<1>(re, im, cy, sy);
    }

    cnot<8, 4>(re, im);
    cnot<4, 2>(re, im);
    cnot<2, 1>(re, im);

    {
        float sz, cz; __sincosf(0.5f * w[8], &sz, &cz);
        rz_gate<8>(re, im, cz, sz);
        float sy, cy; __sincosf(0.5f * w[9], &sy, &cy);
        ry_gate<8>(re, im, cy, sy);
    }
    {
        float sz, cz; __sincosf(0.5f * w[10], &sz, &cz);
        rz_gate<4>(re, im, cz, sz);
        float sy, cy; __sincosf(0.5f * w[11], &sy, &cy);
        ry_gate<4>(re, im, cy, sy);
    }
    {
        float sz, cz; __sincosf(0.5f * w[12], &sz, &cz);
        rz_gate<2>(re, im, cz, sz);
        float sy, cy; __sincosf(0.5f * w[13], &sy, &cy);
        ry_gate<2>(re, im, cy, sy);
    }
    {
        float sz, cz; __sincosf(0.5f * w[14], &sz, &cz);
        rz_gate<1>(re, im, cz, sz);
        float sy, cy; __sincosf(0.5f * w[15], &sy, &cy);
        ry_gate<1>(re, im, cy, sy);
    }

    // --- probabilities and the 4 Z-expectations ---
    float o0 = 0.f, o1 = 0.f, o2 = 0.f, o3 = 0.f;
#pragma unroll
    for (int k = 0; k < DIM; ++k) {
        const float pk = re[k] * re[k] + im[k] * im[k];
        o0 += (k & 8) ? -pk : pk;
        o1 += (k & 4) ? -pk : pk;
        o2 += (k & 2) ? -pk : pk;
        o3 += (k & 1) ? -pk : pk;
    }

    *(float4*)(out + b * 4) = make_float4(o0, o1, o2, o3);
}

extern "C" void kernel_launch(void* const* d_in, const int* in_sizes, int n_in,
                              void* d_out, int out_size, void* d_ws, size_t ws_size,
                              hipStream_t stream) {
    const float* x    = (const float*)d_in[0];
    const float* fm_w = (const float*)d_in[1];
    const float* fm_b = (const float*)d_in[2];
    const float* qw   = (const float*)d_in[3];
    float* out = (float*)d_out;

    const int B = in_sizes[0] / 64;

    qnn_fused<<<(B + TPB - 1) / TPB, TPB, 0, stream>>>(x, fm_w, fm_b, qw, out, B);
}